// Round 15
// baseline (294.733 us; speedup 1.0000x reference)
//
#include <hip/hip_runtime.h>
#include <hip/hip_bf16.h>

// TransNormer: causal linear attention, B=2 N=2048 D=2048 H=16 I=1 K=V=128.
// Precision: all tensors single-plane fp16, 1-pass mfma_f32_16x16x32_f16,
// fp32 accumulation (measured absmax 0.03125 vs threshold 0.109).
// R15: merged qkv GEMM = faithful m201-style 8-phase 256^2 port. BM=BN=256,
// BK=64 as 2 K-halves (kh); 8 waves (2Mx4N, wave 128x64); LDS [2dbuf][2kh]
// slots (128KB). Per phase: {ds_read 8|4 b128; stage ONE half (2 gld16);
// barrier; lgkmcnt(0); setprio+16 MFMA+setprio; [vmcnt(4) at ph2/ph4];
// barrier}. Counted vmcnt keeps 2 stages (4 loads) always in flight -- never
// drains to 0 in the loop. Slot lifetimes verified: a stage writes a slot
// whose last reader finished >=3 barriers earlier; a read's data landed
// >=1 vmcnt(4) earlier. Other kernels: exactly R12 (271us ratchet).

typedef _Float16 f16x8 __attribute__((ext_vector_type(8)));
typedef _Float16 f16x4 __attribute__((ext_vector_type(4)));
typedef float    f32x4 __attribute__((ext_vector_type(4)));

#define DEV static __device__ __forceinline__

// Swizzle for 128B rows (attn K/V/P tiles): XOR byte bits 4-6.
DEV int swzx(int row) { return (((row & 7) ^ ((row >> 3) & 7)) << 4); }
// Swizzle for 64B rows (BK=32/kh-half tiles): XOR byte bits 4-5.
DEV int swz32(int row) { return (((row & 3) ^ ((row >> 2) & 3)) << 4); }

typedef const unsigned int __attribute__((address_space(1)))* gas_t;
typedef unsigned int __attribute__((address_space(3)))* las_t;
DEV void gld16(const void* g, void* l) {   // global -> LDS DMA, 16B/lane
  __builtin_amdgcn_global_load_lds((gas_t)g, (las_t)l, 16, 0, 0);
}

#define SBAR()  __builtin_amdgcn_s_barrier()
#define SCHED() __builtin_amdgcn_sched_barrier(0)
#define LGKM0() asm volatile("s_waitcnt lgkmcnt(0)" ::: "memory")
#define VM4()   asm volatile("s_waitcnt vmcnt(4)" ::: "memory")

// ---------------- cast fp32 -> fp16, contiguous ----------------
__global__ void k_cast_h(const float* __restrict__ in, _Float16* __restrict__ out, int n) {
  int i = (blockIdx.x * blockDim.x + threadIdx.x) * 4;
  int stride = gridDim.x * blockDim.x * 4;
  for (; i < n; i += stride) {
    float4 v = *reinterpret_cast<const float4*>(in + i);
    f16x4 o;
    o[0] = (_Float16)v.x; o[1] = (_Float16)v.y;
    o[2] = (_Float16)v.z; o[3] = (_Float16)v.w;
    *reinterpret_cast<f16x4*>(out + i) = o;
  }
}

// --- 4 weight transposes in one dispatch: out[c][r] = fp16(in[r][c]) ---
__global__ void k_transpose_h4(const float* __restrict__ w0, const float* __restrict__ w1,
                               const float* __restrict__ w2, const float* __restrict__ w3,
                               _Float16* __restrict__ o0, _Float16* __restrict__ o1,
                               _Float16* __restrict__ o2, _Float16* __restrict__ o3) {
  __shared__ float tile[32][33];
  const float* in; _Float16* out;
  switch (blockIdx.z) {
    case 0: in = w0; out = o0; break;
    case 1: in = w1; out = o1; break;
    case 2: in = w2; out = o2; break;
    default: in = w3; out = o3; break;
  }
  int tx = threadIdx.x, ty = threadIdx.y;           // block (32,8)
  int c0 = blockIdx.x * 32, r0 = blockIdx.y * 32;
  #pragma unroll
  for (int j = 0; j < 4; ++j)
    tile[ty + j * 8][tx] = in[(size_t)(r0 + ty + j * 8) * 2048 + c0 + tx];
  __syncthreads();
  #pragma unroll
  for (int j = 0; j < 4; ++j)
    out[(size_t)(c0 + ty + j * 8) * 2048 + r0 + tx] = (_Float16)tile[tx][ty + j * 8];
}

// --- batched transpose: v = qkv[:, 4096+h*128 .. ] (stride 6144) -> (bh,v,n) ---
__global__ void k_transpose_v(const _Float16* __restrict__ in, _Float16* __restrict__ out) {
  __shared__ _Float16 tile[32][33];
  int tx = threadIdx.x, ty = threadIdx.y;           // block (32,8)
  int v0 = blockIdx.x * 32, n0 = blockIdx.y * 32, bh = blockIdx.z;
  int b = bh >> 4, h = bh & 15;
  #pragma unroll
  for (int j = 0; j < 4; ++j)
    tile[ty + j * 8][tx] =
        in[(size_t)(b * 2048 + n0 + ty + j * 8) * 6144 + 4096 + h * 128 + v0 + tx];
  __syncthreads();
  #pragma unroll
  for (int j = 0; j < 4; ++j)
    out[((size_t)bh * 128 + v0 + ty + j * 8) * 2048 + n0 + tx] = tile[tx][ty + j * 8];
}

// ---- 8-phase 256^2 GEMM: C[4096][6144] = A[4096][2048] * B[6144][2048]^T ----
__global__ __launch_bounds__(512) void k_gemm8p(const _Float16* __restrict__ A,
                                                const _Float16* __restrict__ B,
                                                _Float16* __restrict__ C, int ldc) {
  __shared__ __align__(16) _Float16 Asl[4][256 * 32];   // [dbuf*2+kh] 16KB x4
  __shared__ __align__(16) _Float16 Bsl[4][256 * 32];   // [dbuf*2+kh] 16KB x4
  const int tid = threadIdx.x;
  const int lane = tid & 63, w = tid >> 6;              // 8 waves
  const int lr = lane & 15, lg = lane >> 4;
  // XCD-aware block swizzle (384 = 8 x 48; same-XCD blocks share A panels)
  const int lid = ((int)blockIdx.x & 7) * 48 + ((int)blockIdx.x >> 3);
  const int bm = lid / 24, bn = lid % 24;
  const int wr = (w >> 2) * 128, wc = (w & 3) * 64;     // wave tile 128x64

  f32x4 acc[8][4];                                      // [mh*4+m4][nj]
  #pragma unroll
  for (int i = 0; i < 8; ++i)
    #pragma unroll
    for (int j = 0; j < 4; ++j) { f32x4 z = {0.f, 0.f, 0.f, 0.f}; acc[i][j] = z; }

  const _Float16* aBase = A + (size_t)(bm * 256) * 2048;
  const _Float16* bBase = B + (size_t)(bn * 256) * 2048;

  // staging lane constants: row = it*128 + (tid>>2); swz32(row) lane-constant
  const int s_cb = ((tid & 3) * 16) ^ (((((tid >> 2) & 3) ^ ((tid >> 4) & 3))) << 4);
  // read lane constant: swz32 of any frag row == lr-only function
  const int swr = (((lr & 3) ^ ((lr >> 2) & 3)) << 4);

  auto STAGE_A = [&](int T, int kh) {                   // one A half (2 gld16)
    #pragma unroll
    for (int it = 0; it < 2; ++it) {
      int row = it * 128 + (tid >> 2);
      size_t g = (size_t)row * 2048 + T * 64 + kh * 32 + (s_cb >> 1);
      gld16(aBase + g, (char*)Asl[(T & 1) * 2 + kh] + it * 8192 + tid * 16);
    }
  };
  auto STAGE_B = [&](int T, int kh) {                   // one B half (2 gld16)
    #pragma unroll
    for (int it = 0; it < 2; ++it) {
      int row = it * 128 + (tid >> 2);
      size_t g = (size_t)row * 2048 + T * 64 + kh * 32 + (s_cb >> 1);
      gld16(bBase + g, (char*)Bsl[(T & 1) * 2 + kh] + it * 8192 + tid * 16);
    }
  };

  f16x8 af[4], bf[4];
  auto LOAD_B = [&](int d, int kh) {
    #pragma unroll
    for (int nj = 0; nj < 4; ++nj) {
      int br = wc + nj * 16 + lr;
      bf[nj] = *reinterpret_cast<const f16x8*>(
          (const char*)Bsl[d * 2 + kh] + br * 64 + ((lg * 16) ^ swr));
    }
  };
  auto LOAD_A = [&](int d, int kh, int mh) {
    #pragma unroll
    for (int m4 = 0; m4 < 4; ++m4) {
      int ar = wr + mh * 64 + m4 * 16 + lr;
      af[m4] = *reinterpret_cast<const f16x8*>(
          (const char*)Asl[d * 2 + kh] + ar * 64 + ((lg * 16) ^ swr));
    }
  };
  auto MFMA16 = [&](int mh) {
    __builtin_amdgcn_s_setprio(1);
    #pragma unroll
    for (int m4 = 0; m4 < 4; ++m4)
      #pragma unroll
      for (int nj = 0; nj < 4; ++nj)
        acc[mh * 4 + m4][nj] =
            __builtin_amdgcn_mfma_f32_16x16x32_f16(af[m4], bf[nj], acc[mh * 4 + m4][nj], 0, 0, 0);
    __builtin_amdgcn_s_setprio(0);
  };

  // prologue: all 4 halves of K-tile 0; kh0 pair must land (vmcnt(4))
  STAGE_A(0, 0); STAGE_B(0, 0); STAGE_A(0, 1); STAGE_B(0, 1);
  VM4(); SCHED(); SBAR(); SCHED();

  for (int T = 0; T < 32; ++T) {
    const int d = T & 1;
    const bool more = (T + 1 < 32);
    // ---- phase 1: (kh0, mh0); stage A-kh0(T+1) ----
    LOAD_B(d, 0); LOAD_A(d, 0, 0);
    if (more) STAGE_A(T + 1, 0);
    SCHED(); SBAR(); LGKM0(); SCHED();
    MFMA16(0);
    SCHED(); SBAR(); SCHED();
    // ---- phase 2: (kh0, mh1); stage B-kh0(T+1); vmcnt(4) ----
    LOAD_A(d, 0, 1);
    if (more) STAGE_B(T + 1, 0);
    SCHED(); SBAR(); LGKM0(); SCHED();
    MFMA16(1);
    VM4(); SCHED(); SBAR(); SCHED();
    // ---- phase 3: (kh1, mh0); stage A-kh1(T+1) ----
    LOAD_B(d, 1); LOAD_A(d, 1, 0);
    if (more) STAGE_A(T + 1, 1);
    SCHED(); SBAR(); LGKM0(); SCHED();
    MFMA16(0);
    SCHED(); SBAR(); SCHED();
    // ---- phase 4: (kh1, mh1); stage B-kh1(T+1); vmcnt(4) ----
    LOAD_A(d, 1, 1);
    if (more) STAGE_B(T + 1, 1);
    SCHED(); SBAR(); LGKM0(); SCHED();
    MFMA16(1);
    VM4(); SCHED(); SBAR(); SCHED();
  }

  #pragma unroll
  for (int mi = 0; mi < 8; ++mi)
    #pragma unroll
    for (int nj = 0; nj < 4; ++nj)
      #pragma unroll
      for (int r = 0; r < 4; ++r) {
        int grow = bm * 256 + wr + (mi >> 2) * 64 + (mi & 3) * 16 + lg * 4 + r;
        int gcol = bn * 256 + wc + nj * 16 + lr;
        C[(size_t)grow * ldc + gcol] = (_Float16)acc[mi][nj][r];
      }
}

// ---- GEMM 128^2 (final projection, R12-proven): C[4096][2048] fp32 ----
__global__ __launch_bounds__(256) void k_gemm_db(const _Float16* __restrict__ A,
                                                 const _Float16* __restrict__ B,
                                                 float* __restrict__ C, int ldc) {
  __shared__ __align__(16) _Float16 As[2][128 * 64];   // 16KB x2
  __shared__ __align__(16) _Float16 Bs[2][128 * 64];   // 16KB x2
  const int tid = threadIdx.x;
  const int lane = tid & 63, w = tid >> 6;
  const int lr = lane & 15, lg = lane >> 4;
  const int bm = blockIdx.y, bn = blockIdx.x;
  const int wr = (w >> 1) * 64, wc = (w & 1) * 64;

  f32x4 acc[4][4];
  #pragma unroll
  for (int i = 0; i < 4; ++i)
    #pragma unroll
    for (int j = 0; j < 4; ++j) { f32x4 z = {0.f, 0.f, 0.f, 0.f}; acc[i][j] = z; }

  const size_t aOff = (size_t)(bm * 128) * 2048;
  const size_t bOff = (size_t)(bn * 128) * 2048;

  auto STAGE = [&](int kt, int bufi) {
    #pragma unroll
    for (int it = 0; it < 4; ++it) {               // 16B/lane DMA, lane-linear dest
      int row = it * 32 + (tid >> 3);
      int cb  = ((tid & 7) * 16) ^ swzx(row);      // pre-swizzled source col (bytes)
      size_t g = (size_t)row * 2048 + kt * 64 + (cb >> 1);
      int ld = it * 4096 + tid * 16;
      gld16(A + aOff + g, (char*)As[bufi] + ld);
      gld16(B + bOff + g, (char*)Bs[bufi] + ld);
    }
  };

  STAGE(0, 0);
  asm volatile("s_waitcnt vmcnt(0)" ::: "memory");
  SBAR(); SCHED();

  for (int kt = 0; kt < 32; ++kt) {
    const int cur = kt & 1;
    if (kt + 1 < 32) STAGE(kt + 1, cur ^ 1);
    SCHED();
    #pragma unroll
    for (int ks = 0; ks < 2; ++ks) {
      f16x8 af[4], bf[4];
      #pragma unroll
      for (int f = 0; f < 4; ++f) {
        int ar = wr + f * 16 + lr;
        af[f] = *reinterpret_cast<const f16x8*>((const char*)As[cur] + ar * 128 +
                                                ((ks * 64 + lg * 16) ^ swzx(ar)));
        int br = wc + f * 16 + lr;
        bf[f] = *reinterpret_cast<const f16x8*>((const char*)Bs[cur] + br * 128 +
                                                ((ks * 64 + lg * 16) ^ swzx(br)));
      }
      __builtin_amdgcn_s_setprio(1);
      #pragma unroll
      for (int i = 0; i < 4; ++i)
        #pragma unroll
        for (int j = 0; j < 4; ++j)
          acc[i][j] = __builtin_amdgcn_mfma_f32_16x16x32_f16(af[i], bf[j], acc[i][j], 0, 0, 0);
      __builtin_amdgcn_s_setprio(0);
    }
    asm volatile("s_waitcnt vmcnt(0)" ::: "memory");
    SBAR(); SCHED();
  }

  #pragma unroll
  for (int fm = 0; fm < 4; ++fm)
    #pragma unroll
    for (int fn = 0; fn < 4; ++fn)
      #pragma unroll
      for (int r = 0; r < 4; ++r) {
        int grow = bm * 128 + wr + fm * 16 + lg * 4 + r;
        int gcol = bn * 128 + wc + fn * 16 + lr;
        C[(size_t)grow * ldc + gcol] = acc[fm][fn][r];
      }
}

// ---------------- fused masked attention + RMSNorm, fp16 1-pass ----------
// 4 waves (256 thr), QBLK=64, KVBLK=64. grid (32, 16): block j does q-tiles
// {j, 31-j} -> uniform 33 KV-tile-units; 512 blocks = 2/CU co-resident.
__global__ __launch_bounds__(256) void k_attn1(const _Float16* __restrict__ qkv,
                                               const _Float16* __restrict__ vt,
                                               const float* __restrict__ nm,
                                               const float* __restrict__ rms_scale,
                                               _Float16* __restrict__ y) {
  __shared__ __align__(16) _Float16 Ks[2][64 * 128];   // [m][k] 16KB x2
  __shared__ __align__(16) _Float16 Vs[2][128 * 64];   // [v][m] 16KB x2
  __shared__ __align__(16) _Float16 Ps[64 * 64];       // [n][m] 8KB
  const int tid = threadIdx.x;
  const int lane = tid & 63, w = tid >> 6;             // w in 0..3
  const int lr = lane & 15, lg = lane >> 4;
  const int bh = blockIdx.x, b = bh >> 4, h = bh & 15;
  const _Float16* qb = qkv + (size_t)b * 2048 * 6144 + h * 128;          // q cols
  const _Float16* kb = qkv + (size_t)b * 2048 * 6144 + 2048 + h * 128;   // k cols
  const size_t vbase = (size_t)bh * 128 * 2048;                          // (bh,v,n)

  const int krow = tid >> 4, kc = tid & 15;    // K stage: 16 rows/it, 16 chunks
  const int vrow = tid >> 3, vc = tid & 7;     // V stage: 32 rows/it, 8 chunks

  auto STAGE = [&](int t, int bufi) {
    #pragma unroll
    for (int it = 0; it < 4; ++it) {
      int kr = it * 16 + krow;
      int gk = ((kc * 16) ^ swzx(kr)) >> 1;
      gld16(kb + (size_t)(t * 64 + kr) * 6144 + gk,
            (char*)Ks[bufi] + it * 4096 + tid * 16);
      int vr = it * 32 + vrow;
      int gv = ((vc * 16) ^ swzx(vr)) >> 1;
      gld16(vt + vbase + (size_t)vr * 2048 + t * 64 + gv,
            (char*)Vs[bufi] + it * 4096 + tid * 16);
    }
  };

  #pragma unroll
  for (int pi = 0; pi < 2; ++pi) {
    const int qt = pi ? (31 - (int)blockIdx.y) : (int)blockIdx.y;  // 64-row q-tile
    const int nT = qt + 1;

    f16x8 aq[4];
    {
      const _Float16* qrow = qb + (size_t)(qt * 64 + w * 16 + lr) * 6144;
      #pragma unroll
      for (int ks = 0; ks < 4; ++ks)
        aq[ks] = *reinterpret_cast<const f16x8*>(qrow + ks * 32 + lg * 8);
    }

    f32x4 accY[8];
    #pragma unroll
    for (int i = 0; i < 8; ++i) { f32x4 z = {0.f, 0.f, 0.f, 0.f}; accY[i] = z; }

    STAGE(0, 0);
    asm volatile("s_waitcnt vmcnt(0)" ::: "memory");
    SBAR(); SCHED();

    for (int t = 0; t < nT; ++t) {
      const int cur = t & 1;

      float nmv[4][4];                            // mask for tile t -- FIRST
      #pragma unroll
      for (int fm = 0; fm < 4; ++fm)
        #pragma unroll
        for (int r = 0; r < 4; ++r)
          nmv[fm][r] = nm[(size_t)(qt * 64 + w * 16 + lg * 4 + r) * 2048 +
                          t * 64 + fm * 16 + lr];
      SCHED();                                    // pin: nm loads before DMA

      if (t + 1 < nT) STAGE(t + 1, cur ^ 1);      // DMA overlaps compute below

      f32x4 accS[4];
      #pragma unroll
      for (int i = 0; i < 4; ++i) { f32x4 z = {0.f, 0.f, 0.f, 0.f}; accS[i] = z; }
      __builtin_amdgcn_s_setprio(1);
      #pragma unroll
      for (int ks = 0; ks < 4; ++ks) {
        #pragma unroll
        for (int fm = 0; fm < 4; ++fm) {
          int br = fm * 16 + lr;
          f16x8 bk = *reinterpret_cast<const f16x8*>(
              (const char*)Ks[cur] + br * 256 + ((ks * 64 + lg * 16) ^ swzx(br)));
          accS[fm] = __builtin_amdgcn_mfma_f32_16x16x32_f16(aq[ks], bk, accS[fm], 0, 0, 0);
        }
      }
      __builtin_amdgcn_s_setprio(0);

      #pragma unroll
      for (int fm = 0; fm < 4; ++fm)
        #pragma unroll
        for (int r = 0; r < 4; ++r) {
          float pv = accS[fm][r] * nmv[fm][r];
          int pr = w * 16 + lg * 4 + r, pc = fm * 16 + lr;
          *reinterpret_cast<_Float16*>((char*)Ps + pr * 128 + ((pc * 2) ^ swzx(pr))) =
              (_Float16)pv;
        }

      __builtin_amdgcn_s_setprio(1);
      #pragma unroll
      for (int ks = 0; ks < 2; ++ks) {
        int ar = w * 16 + lr;
        f16x8 ap = *reinterpret_cast<const f16x8*>(
            (const char*)Ps + ar * 128 + ((ks * 64 + lg * 16) ^ swzx(ar)));
        #pragma unroll
        for (int fv = 0; fv < 8; ++fv) {
          int br = fv * 16 + lr;
          f16x8 bv = *reinterpret_cast<const f16x8*>(
              (const char*)Vs[cur] + br * 128 + ((ks * 64 + lg * 16) ^ swzx(br)));
          accY[fv] = __builtin_amdgcn_mfma_f32_16x16x32_f16(ap, bv, accY[fv], 0, 0, 0);
        }
      }
      __builtin_amdgcn_s_setprio(0);

      asm volatile("s_waitcnt vmcnt(0)" ::: "memory");
      SBAR(); SCHED();
    }

    // epilogue: RMSNorm over V=128 per row, write y fp16 (b,n,h,v)
    #pragma unroll
    for (int r = 0; r < 4; ++r) {
      float sq = 0.f;
      #pragma unroll
      for (int fv = 0; fv < 8; ++fv) { float yy = accY[fv][r]; sq += yy * yy; }
      sq += __shfl_xor(sq, 1); sq += __shfl_xor(sq, 2);
      sq += __shfl_xor(sq, 4); sq += __shfl_xor(sq, 8);
      float scale = rsqrtf(sq * (1.0f / 128.0f) + 1e-6f);
      int nrow = qt * 64 + w * 16 + lg * 4 + r;
      size_t orow = ((size_t)b * 2048 + nrow) * 2048 + (size_t)h * 128;
      #pragma unroll
      for (int fv = 0; fv < 8; ++fv) {
        int col = fv * 16 + lr;
        y[orow + col] = (_Float16)(accY[fv][r] * scale * rms_scale[col]);
      }
    }
  }
}

extern "C" void kernel_launch(void* const* d_in, const int* in_sizes, int n_in,
                              void* d_out, int out_size, void* d_ws, size_t ws_size,
                              hipStream_t stream) {
  (void)in_sizes; (void)n_in; (void)out_size; (void)ws_size;
  const float* x  = (const float*)d_in[0];
  const float* nm = (const float*)d_in[1];
  const float* wq = (const float*)d_in[2];
  const float* wk = (const float*)d_in[3];
  const float* wv = (const float*)d_in[4];
  const float* rs = (const float*)d_in[5];
  const float* wo = (const float*)d_in[6];

  _Float16* p = (_Float16*)d_ws;                 // ~118 MB of fp16 planes
  _Float16* xf  = p; p += 8388608;               // x fp16; reused as y after attn
  _Float16* wt3 = p; p += 12582912;              // [wqT; wkT; wvT] (6144 x 2048)
  _Float16* wto = p; p += 4194304;               // woT
  _Float16* qkv = p; p += 25165824;              // (b,n) x (q|k|v) (4096 x 6144)
  _Float16* vtf = p; p += 8388608;               // v^T (b*h, v, n)

  k_cast_h<<<dim3(2048), dim3(256), 0, stream>>>(x, xf, 8388608);

  k_transpose_h4<<<dim3(64, 64, 4), dim3(32, 8), 0, stream>>>(
      wq, wk, wv, wo, wt3, wt3 + 4194304, wt3 + 8388608, wto);

  // merged q|k|v projection: C (4096 x 6144), 8-phase 256^2, 384 blocks
  k_gemm8p<<<dim3(384), dim3(512), 0, stream>>>(xf, wt3, qkv, 6144);
  k_transpose_v<<<dim3(4, 64, 32), dim3(32, 8), 0, stream>>>(qkv, vtf);

  // y written into the (now dead) x plane
  k_attn1<<<dim3(32, 16), dim3(256), 0, stream>>>(qkv, vtf, nm, rs, xf);

  k_gemm_db<<<dim3(16, 32), dim3(256), 0, stream>>>(xf, wto, (float*)d_out, 2048);
}

// Round 16
// 282.879 us; speedup vs baseline: 1.0419x; 1.0419x over previous
//
#include <hip/hip_runtime.h>
#include <hip/hip_bf16.h>

// TransNormer: causal linear attention, B=2 N=2048 D=2048 H=16 I=1 K=V=128.
// Precision: all tensors single-plane fp16, 1-pass mfma_f32_16x16x32_f16,
// fp32 accumulation (measured absmax 0.03125 vs threshold 0.109).
// R16 = R12 (271us ratchet: 128^2 dbuf GEMM, drain-at-tile-end; attn 4-wave
// QBLK=64 paired) + T1 XCD-chunked block swizzle on both GEMMs: each XCD gets
// a contiguous chunk (4 bm-rows x all bn) so A-panels are L2-resident instead
// of refetched by round-robin-scattered blocks (R12 FETCH 106MB vs 41 ideal).

typedef _Float16 f16x8 __attribute__((ext_vector_type(8)));
typedef _Float16 f16x4 __attribute__((ext_vector_type(4)));
typedef float    f32x4 __attribute__((ext_vector_type(4)));

#define DEV static __device__ __forceinline__

// Swizzle for 128B rows (attn K/V/P + GEMM BK=64 tiles): XOR byte bits 4-6.
DEV int swzx(int row) { return (((row & 7) ^ ((row >> 3) & 7)) << 4); }

typedef const unsigned int __attribute__((address_space(1)))* gas_t;
typedef unsigned int __attribute__((address_space(3)))* las_t;
DEV void gld16(const void* g, void* l) {   // global -> LDS DMA, 16B/lane
  __builtin_amdgcn_global_load_lds((gas_t)g, (las_t)l, 16, 0, 0);
}

// ---------------- cast fp32 -> fp16, contiguous ----------------
__global__ void k_cast_h(const float* __restrict__ in, _Float16* __restrict__ out, int n) {
  int i = (blockIdx.x * blockDim.x + threadIdx.x) * 4;
  int stride = gridDim.x * blockDim.x * 4;
  for (; i < n; i += stride) {
    float4 v = *reinterpret_cast<const float4*>(in + i);
    f16x4 o;
    o[0] = (_Float16)v.x; o[1] = (_Float16)v.y;
    o[2] = (_Float16)v.z; o[3] = (_Float16)v.w;
    *reinterpret_cast<f16x4*>(out + i) = o;
  }
}

// --- 4 weight transposes in one dispatch: out[c][r] = fp16(in[r][c]) ---
__global__ void k_transpose_h4(const float* __restrict__ w0, const float* __restrict__ w1,
                               const float* __restrict__ w2, const float* __restrict__ w3,
                               _Float16* __restrict__ o0, _Float16* __restrict__ o1,
                               _Float16* __restrict__ o2, _Float16* __restrict__ o3) {
  __shared__ float tile[32][33];
  const float* in; _Float16* out;
  switch (blockIdx.z) {
    case 0: in = w0; out = o0; break;
    case 1: in = w1; out = o1; break;
    case 2: in = w2; out = o2; break;
    default: in = w3; out = o3; break;
  }
  int tx = threadIdx.x, ty = threadIdx.y;           // block (32,8)
  int c0 = blockIdx.x * 32, r0 = blockIdx.y * 32;
  #pragma unroll
  for (int j = 0; j < 4; ++j)
    tile[ty + j * 8][tx] = in[(size_t)(r0 + ty + j * 8) * 2048 + c0 + tx];
  __syncthreads();
  #pragma unroll
  for (int j = 0; j < 4; ++j)
    out[(size_t)(c0 + ty + j * 8) * 2048 + r0 + tx] = (_Float16)tile[tx][ty + j * 8];
}

// --- batched transpose: v = qkv[:, 4096+h*128 .. ] (stride 6144) -> (bh,v,n) ---
__global__ void k_transpose_v(const _Float16* __restrict__ in, _Float16* __restrict__ out) {
  __shared__ _Float16 tile[32][33];
  int tx = threadIdx.x, ty = threadIdx.y;           // block (32,8)
  int v0 = blockIdx.x * 32, n0 = blockIdx.y * 32, bh = blockIdx.z;
  int b = bh >> 4, h = bh & 15;
  #pragma unroll
  for (int j = 0; j < 4; ++j)
    tile[ty + j * 8][tx] =
        in[(size_t)(b * 2048 + n0 + ty + j * 8) * 6144 + 4096 + h * 128 + v0 + tx];
  __syncthreads();
  #pragma unroll
  for (int j = 0; j < 4; ++j)
    out[((size_t)bh * 128 + v0 + ty + j * 8) * 2048 + n0 + tx] = tile[tx][ty + j * 8];
}

// ---- GEMM: C[4096][NBN*128] = A[4096][2048] * B[NBN*128][2048]^T, fp16 ----
// 128x128 tile, BK=64, 4 waves, double-buffered gld_lds pipeline (64KB LDS,
// 2 blocks/CU): STAGE(kt+1) at tile top, compute kt, drain at tile END.
// 1D grid + XCD-chunked swizzle (grid%8==0): each XCD owns a contiguous chunk
// of 4 bm-rows x NBN bn -> A-panel (512KB) L2-resident, reused NBN times.
// OUTF32: 1 -> fp32 C (d_out), 0 -> fp16 C. ldc = C row stride.
template <int OUTF32>
__global__ __launch_bounds__(256) void k_gemm_db(const _Float16* __restrict__ A,
                                                 const _Float16* __restrict__ B,
                                                 void* __restrict__ C, int ldc, int nbn) {
  __shared__ __align__(16) _Float16 As[2][128 * 64];   // 16KB x2
  __shared__ __align__(16) _Float16 Bs[2][128 * 64];   // 16KB x2
  const int tid = threadIdx.x;
  const int lane = tid & 63, w = tid >> 6;
  const int lr = lane & 15, lg = lane >> 4;
  // XCD-chunked bijective swizzle (consecutive HW blockIdx round-robin XCDs)
  const int bid = (int)blockIdx.x;
  const int cpx = (int)gridDim.x >> 3;                 // blocks per XCD chunk
  const int lid = (bid & 7) * cpx + (bid >> 3);
  const int bm = lid / nbn, bn = lid % nbn;
  const int wr = (w >> 1) * 64, wc = (w & 1) * 64;

  f32x4 acc[4][4];
  #pragma unroll
  for (int i = 0; i < 4; ++i)
    #pragma unroll
    for (int j = 0; j < 4; ++j) { f32x4 z = {0.f, 0.f, 0.f, 0.f}; acc[i][j] = z; }

  const size_t aOff = (size_t)(bm * 128) * 2048;
  const size_t bOff = (size_t)(bn * 128) * 2048;

  auto STAGE = [&](int kt, int bufi) {
    #pragma unroll
    for (int it = 0; it < 4; ++it) {               // 16B/lane DMA, lane-linear dest
      int row = it * 32 + (tid >> 3);
      int cb  = ((tid & 7) * 16) ^ swzx(row);      // pre-swizzled source col (bytes)
      size_t g = (size_t)row * 2048 + kt * 64 + (cb >> 1);
      int ld = it * 4096 + tid * 16;               // bytes: 32 rows x 128 B per it
      gld16(A + aOff + g, (char*)As[bufi] + ld);
      gld16(B + bOff + g, (char*)Bs[bufi] + ld);
    }
  };

  STAGE(0, 0);
  asm volatile("s_waitcnt vmcnt(0)" ::: "memory");
  __builtin_amdgcn_s_barrier();
  __builtin_amdgcn_sched_barrier(0);

  for (int kt = 0; kt < 32; ++kt) {
    const int cur = kt & 1;
    if (kt + 1 < 32) STAGE(kt + 1, cur ^ 1);       // DMA overlaps compute below
    __builtin_amdgcn_sched_barrier(0);

    #pragma unroll
    for (int ks = 0; ks < 2; ++ks) {
      f16x8 af[4], bf[4];
      #pragma unroll
      for (int f = 0; f < 4; ++f) {
        int ar = wr + f * 16 + lr;
        af[f] = *reinterpret_cast<const f16x8*>((const char*)As[cur] + ar * 128 +
                                                ((ks * 64 + lg * 16) ^ swzx(ar)));
        int br = wc + f * 16 + lr;
        bf[f] = *reinterpret_cast<const f16x8*>((const char*)Bs[cur] + br * 128 +
                                                ((ks * 64 + lg * 16) ^ swzx(br)));
      }
      __builtin_amdgcn_s_setprio(1);
      #pragma unroll
      for (int i = 0; i < 4; ++i)
        #pragma unroll
        for (int j = 0; j < 4; ++j)
          acc[i][j] = __builtin_amdgcn_mfma_f32_16x16x32_f16(af[i], bf[j], acc[i][j], 0, 0, 0);
      __builtin_amdgcn_s_setprio(0);
    }

    // next tile's DMA landed (hidden under the 32 MFMAs above); rotate
    asm volatile("s_waitcnt vmcnt(0)" ::: "memory");
    __builtin_amdgcn_s_barrier();
    __builtin_amdgcn_sched_barrier(0);
  }

  #pragma unroll
  for (int fm = 0; fm < 4; ++fm)
    #pragma unroll
    for (int fn = 0; fn < 4; ++fn)
      #pragma unroll
      for (int r = 0; r < 4; ++r) {
        int grow = bm * 128 + wr + fm * 16 + lg * 4 + r;   // D row = (lane>>4)*4+r
        int gcol = bn * 128 + wc + fn * 16 + lr;           // D col = lane&15
        float v = acc[fm][fn][r];
        size_t o = (size_t)grow * ldc + gcol;
        if (OUTF32) ((float*)C)[o] = v;
        else        ((_Float16*)C)[o] = (_Float16)v;
      }
}

// ---------------- fused masked attention + RMSNorm, fp16 1-pass ----------
// 4 waves (256 thr), QBLK=64, KVBLK=64. grid (32, 16): block j does q-tiles
// {j, 31-j} -> uniform 33 KV-tile-units; 512 blocks = 2/CU co-resident.
__global__ __launch_bounds__(256) void k_attn1(const _Float16* __restrict__ qkv,
                                               const _Float16* __restrict__ vt,
                                               const float* __restrict__ nm,
                                               const float* __restrict__ rms_scale,
                                               _Float16* __restrict__ y) {
  __shared__ __align__(16) _Float16 Ks[2][64 * 128];   // [m][k] 16KB x2
  __shared__ __align__(16) _Float16 Vs[2][128 * 64];   // [v][m] 16KB x2
  __shared__ __align__(16) _Float16 Ps[64 * 64];       // [n][m] 8KB
  const int tid = threadIdx.x;
  const int lane = tid & 63, w = tid >> 6;             // w in 0..3
  const int lr = lane & 15, lg = lane >> 4;
  const int bh = blockIdx.x, b = bh >> 4, h = bh & 15;
  const _Float16* qb = qkv + (size_t)b * 2048 * 6144 + h * 128;          // q cols
  const _Float16* kb = qkv + (size_t)b * 2048 * 6144 + 2048 + h * 128;   // k cols
  const size_t vbase = (size_t)bh * 128 * 2048;                          // (bh,v,n)

  const int krow = tid >> 4, kc = tid & 15;    // K stage: 16 rows/it, 16 chunks
  const int vrow = tid >> 3, vc = tid & 7;     // V stage: 32 rows/it, 8 chunks

  auto STAGE = [&](int t, int bufi) {
    #pragma unroll
    for (int it = 0; it < 4; ++it) {
      int kr = it * 16 + krow;
      int gk = ((kc * 16) ^ swzx(kr)) >> 1;
      gld16(kb + (size_t)(t * 64 + kr) * 6144 + gk,
            (char*)Ks[bufi] + it * 4096 + tid * 16);   // 16 rows x 256 B per it
      int vr = it * 32 + vrow;
      int gv = ((vc * 16) ^ swzx(vr)) >> 1;
      gld16(vt + vbase + (size_t)vr * 2048 + t * 64 + gv,
            (char*)Vs[bufi] + it * 4096 + tid * 16);   // 32 rows x 128 B per it
    }
  };

  #pragma unroll
  for (int pi = 0; pi < 2; ++pi) {
    const int qt = pi ? (31 - (int)blockIdx.y) : (int)blockIdx.y;  // 64-row q-tile
    const int nT = qt + 1;

    f16x8 aq[4];
    {
      const _Float16* qrow = qb + (size_t)(qt * 64 + w * 16 + lr) * 6144;
      #pragma unroll
      for (int ks = 0; ks < 4; ++ks)
        aq[ks] = *reinterpret_cast<const f16x8*>(qrow + ks * 32 + lg * 8);
    }

    f32x4 accY[8];
    #pragma unroll
    for (int i = 0; i < 8; ++i) { f32x4 z = {0.f, 0.f, 0.f, 0.f}; accY[i] = z; }

    STAGE(0, 0);
    asm volatile("s_waitcnt vmcnt(0)" ::: "memory");
    __builtin_amdgcn_s_barrier();
    __builtin_amdgcn_sched_barrier(0);

    for (int t = 0; t < nT; ++t) {
      const int cur = t & 1;

      float nmv[4][4];                            // mask for tile t -- FIRST
      #pragma unroll
      for (int fm = 0; fm < 4; ++fm)
        #pragma unroll
        for (int r = 0; r < 4; ++r)
          nmv[fm][r] = nm[(size_t)(qt * 64 + w * 16 + lg * 4 + r) * 2048 +
                          t * 64 + fm * 16 + lr];
      __builtin_amdgcn_sched_barrier(0);          // pin: nm loads before DMA

      if (t + 1 < nT) STAGE(t + 1, cur ^ 1);      // DMA overlaps compute below

      f32x4 accS[4];
      #pragma unroll
      for (int i = 0; i < 4; ++i) { f32x4 z = {0.f, 0.f, 0.f, 0.f}; accS[i] = z; }
      __builtin_amdgcn_s_setprio(1);
      #pragma unroll
      for (int ks = 0; ks < 4; ++ks) {
        #pragma unroll
        for (int fm = 0; fm < 4; ++fm) {
          int br = fm * 16 + lr;
          f16x8 bk = *reinterpret_cast<const f16x8*>(
              (const char*)Ks[cur] + br * 256 + ((ks * 64 + lg * 16) ^ swzx(br)));
          accS[fm] = __builtin_amdgcn_mfma_f32_16x16x32_f16(aq[ks], bk, accS[fm], 0, 0, 0);
        }
      }
      __builtin_amdgcn_s_setprio(0);

      #pragma unroll
      for (int fm = 0; fm < 4; ++fm)
        #pragma unroll
        for (int r = 0; r < 4; ++r) {
          float pv = accS[fm][r] * nmv[fm][r];
          int pr = w * 16 + lg * 4 + r, pc = fm * 16 + lr;
          *reinterpret_cast<_Float16*>((char*)Ps + pr * 128 + ((pc * 2) ^ swzx(pr))) =
              (_Float16)pv;
        }

      __builtin_amdgcn_s_setprio(1);
      #pragma unroll
      for (int ks = 0; ks < 2; ++ks) {
        int ar = w * 16 + lr;
        f16x8 ap = *reinterpret_cast<const f16x8*>(
            (const char*)Ps + ar * 128 + ((ks * 64 + lg * 16) ^ swzx(ar)));
        #pragma unroll
        for (int fv = 0; fv < 8; ++fv) {
          int br = fv * 16 + lr;
          f16x8 bv = *reinterpret_cast<const f16x8*>(
              (const char*)Vs[cur] + br * 128 + ((ks * 64 + lg * 16) ^ swzx(br)));
          accY[fv] = __builtin_amdgcn_mfma_f32_16x16x32_f16(ap, bv, accY[fv], 0, 0, 0);
        }
      }
      __builtin_amdgcn_s_setprio(0);

      asm volatile("s_waitcnt vmcnt(0)" ::: "memory");
      __builtin_amdgcn_s_barrier();
      __builtin_amdgcn_sched_barrier(0);
    }

    // epilogue: RMSNorm over V=128 per row, write y fp16 (b,n,h,v)
    #pragma unroll
    for (int r = 0; r < 4; ++r) {
      float sq = 0.f;
      #pragma unroll
      for (int fv = 0; fv < 8; ++fv) { float yy = accY[fv][r]; sq += yy * yy; }
      sq += __shfl_xor(sq, 1); sq += __shfl_xor(sq, 2);
      sq += __shfl_xor(sq, 4); sq += __shfl_xor(sq, 8);
      float scale = rsqrtf(sq * (1.0f / 128.0f) + 1e-6f);
      int nrow = qt * 64 + w * 16 + lg * 4 + r;
      size_t orow = ((size_t)b * 2048 + nrow) * 2048 + (size_t)h * 128;
      #pragma unroll
      for (int fv = 0; fv < 8; ++fv) {
        int col = fv * 16 + lr;
        y[orow + col] = (_Float16)(accY[fv][r] * scale * rms_scale[col]);
      }
    }
  }
}

extern "C" void kernel_launch(void* const* d_in, const int* in_sizes, int n_in,
                              void* d_out, int out_size, void* d_ws, size_t ws_size,
                              hipStream_t stream) {
  (void)in_sizes; (void)n_in; (void)out_size; (void)ws_size;
  const float* x  = (const float*)d_in[0];
  const float* nm = (const float*)d_in[1];
  const float* wq = (const float*)d_in[2];
  const float* wk = (const float*)d_in[3];
  const float* wv = (const float*)d_in[4];
  const float* rs = (const float*)d_in[5];
  const float* wo = (const float*)d_in[6];

  _Float16* p = (_Float16*)d_ws;                 // ~118 MB of fp16 planes
  _Float16* xf  = p; p += 8388608;               // x fp16; reused as y after attn
  _Float16* wt3 = p; p += 12582912;              // [wqT; wkT; wvT] (6144 x 2048)
  _Float16* wto = p; p += 4194304;               // woT
  _Float16* qkv = p; p += 25165824;              // (b,n) x (q|k|v) (4096 x 6144)
  _Float16* vtf = p; p += 8388608;               // v^T (b*h, v, n)

  k_cast_h<<<dim3(2048), dim3(256), 0, stream>>>(x, xf, 8388608);

  k_transpose_h4<<<dim3(64, 64, 4), dim3(32, 8), 0, stream>>>(
      wq, wk, wv, wo, wt3, wt3 + 4194304, wt3 + 8388608, wto);

  // merged q|k|v projection: C (4096 x 6144), BK=64 dbuf + XCD-chunked swizzle
  k_gemm_db<0><<<dim3(1536), dim3(256), 0, stream>>>(xf, wt3, qkv, 6144, 48);
  k_transpose_v<<<dim3(4, 64, 32), dim3(32, 8), 0, stream>>>(qkv, vtf);

  // y written into the (now dead) x plane
  k_attn1<<<dim3(32, 16), dim3(256), 0, stream>>>(qkv, vtf, nm, rs, xf);

  k_gemm_db<1><<<dim3(512), dim3(256), 0, stream>>>(xf, wto, d_out, 2048, 16);
}

// Round 17
// 271.201 us; speedup vs baseline: 1.0868x; 1.0431x over previous
//
#include <hip/hip_runtime.h>
#include <hip/hip_bf16.h>

// TransNormer: causal linear attention, B=2 N=2048 D=2048 H=16 I=1 K=V=128.
// Precision: all tensors single-plane fp16, 1-pass mfma_f32_16x16x32_f16,
// fp32 accumulation (measured absmax 0.03125 vs threshold 0.109).
// R17 = exact revert to R12 (271us ratchet). Post-mortem table of GEMM
// restructures: R12 dbuf/drain-at-end 126us BEST; R10 coarse-phase 147;
// R11 reg-stage spill 538; R13 counted 4-buf 133; R14 4-blk/CU 140;
// R15 8-phase 154; R16 XCD-chunk swizzle 137 (FETCH 3x -- B-panel thrash).

typedef _Float16 f16x8 __attribute__((ext_vector_type(8)));
typedef _Float16 f16x4 __attribute__((ext_vector_type(4)));
typedef float    f32x4 __attribute__((ext_vector_type(4)));

#define DEV static __device__ __forceinline__

// XOR swizzle of byte bits 4-6 (bank-group spread); 16B blocks are atomic.
DEV int swzx(int row) { return (((row & 7) ^ ((row >> 3) & 7)) << 4); }

typedef const unsigned int __attribute__((address_space(1)))* gas_t;
typedef unsigned int __attribute__((address_space(3)))* las_t;
DEV void gld16(const void* g, void* l) {   // global -> LDS DMA, 16B/lane
  __builtin_amdgcn_global_load_lds((gas_t)g, (las_t)l, 16, 0, 0);
}

// ---------------- cast fp32 -> fp16, contiguous ----------------
__global__ void k_cast_h(const float* __restrict__ in, _Float16* __restrict__ out, int n) {
  int i = (blockIdx.x * blockDim.x + threadIdx.x) * 4;
  int stride = gridDim.x * blockDim.x * 4;
  for (; i < n; i += stride) {
    float4 v = *reinterpret_cast<const float4*>(in + i);
    f16x4 o;
    o[0] = (_Float16)v.x; o[1] = (_Float16)v.y;
    o[2] = (_Float16)v.z; o[3] = (_Float16)v.w;
    *reinterpret_cast<f16x4*>(out + i) = o;
  }
}

// --- 4 weight transposes in one dispatch: out[c][r] = fp16(in[r][c]) ---
__global__ void k_transpose_h4(const float* __restrict__ w0, const float* __restrict__ w1,
                               const float* __restrict__ w2, const float* __restrict__ w3,
                               _Float16* __restrict__ o0, _Float16* __restrict__ o1,
                               _Float16* __restrict__ o2, _Float16* __restrict__ o3) {
  __shared__ float tile[32][33];
  const float* in; _Float16* out;
  switch (blockIdx.z) {
    case 0: in = w0; out = o0; break;
    case 1: in = w1; out = o1; break;
    case 2: in = w2; out = o2; break;
    default: in = w3; out = o3; break;
  }
  int tx = threadIdx.x, ty = threadIdx.y;           // block (32,8)
  int c0 = blockIdx.x * 32, r0 = blockIdx.y * 32;
  #pragma unroll
  for (int j = 0; j < 4; ++j)
    tile[ty + j * 8][tx] = in[(size_t)(r0 + ty + j * 8) * 2048 + c0 + tx];
  __syncthreads();
  #pragma unroll
  for (int j = 0; j < 4; ++j)
    out[(size_t)(c0 + ty + j * 8) * 2048 + r0 + tx] = (_Float16)tile[tx][ty + j * 8];
}

// --- batched transpose: v = qkv[:, 4096+h*128 .. ] (stride 6144) -> (bh,v,n) ---
__global__ void k_transpose_v(const _Float16* __restrict__ in, _Float16* __restrict__ out) {
  __shared__ _Float16 tile[32][33];
  int tx = threadIdx.x, ty = threadIdx.y;           // block (32,8)
  int v0 = blockIdx.x * 32, n0 = blockIdx.y * 32, bh = blockIdx.z;
  int b = bh >> 4, h = bh & 15;
  #pragma unroll
  for (int j = 0; j < 4; ++j)
    tile[ty + j * 8][tx] =
        in[(size_t)(b * 2048 + n0 + ty + j * 8) * 6144 + 4096 + h * 128 + v0 + tx];
  __syncthreads();
  #pragma unroll
  for (int j = 0; j < 4; ++j)
    out[((size_t)bh * 128 + v0 + ty + j * 8) * 2048 + n0 + tx] = tile[tx][ty + j * 8];
}

// ---- GEMM: C[4096][Nt*128] = A[4096][2048] * B[Nt*128][2048]^T, fp16 ----
// 128x128 tile, BK=64, 4 waves, double-buffered gld_lds pipeline (64KB LDS,
// 2 blocks/CU): STAGE(kt+1) at tile top, compute kt, drain at tile END.
// OUTF32: 1 -> fp32 C (d_out), 0 -> fp16 C. ldc = C row stride.
template <int OUTF32>
__global__ __launch_bounds__(256) void k_gemm_db(const _Float16* __restrict__ A,
                                                 const _Float16* __restrict__ B,
                                                 void* __restrict__ C, int ldc) {
  __shared__ __align__(16) _Float16 As[2][128 * 64];   // 16KB x2
  __shared__ __align__(16) _Float16 Bs[2][128 * 64];   // 16KB x2
  const int tid = threadIdx.x;
  const int lane = tid & 63, w = tid >> 6;
  const int lr = lane & 15, lg = lane >> 4;
  const int bm = blockIdx.y, bn = blockIdx.x;
  const int wr = (w >> 1) * 64, wc = (w & 1) * 64;

  f32x4 acc[4][4];
  #pragma unroll
  for (int i = 0; i < 4; ++i)
    #pragma unroll
    for (int j = 0; j < 4; ++j) { f32x4 z = {0.f, 0.f, 0.f, 0.f}; acc[i][j] = z; }

  const size_t aOff = (size_t)(bm * 128) * 2048;
  const size_t bOff = (size_t)(bn * 128) * 2048;

  auto STAGE = [&](int kt, int bufi) {
    #pragma unroll
    for (int it = 0; it < 4; ++it) {               // 16B/lane DMA, lane-linear dest
      int row = it * 32 + (tid >> 3);
      int cb  = ((tid & 7) * 16) ^ swzx(row);      // pre-swizzled source col (bytes)
      size_t g = (size_t)row * 2048 + kt * 64 + (cb >> 1);
      int ld = it * 4096 + tid * 16;               // bytes: 32 rows x 128 B per it
      gld16(A + aOff + g, (char*)As[bufi] + ld);
      gld16(B + bOff + g, (char*)Bs[bufi] + ld);
    }
  };

  STAGE(0, 0);
  asm volatile("s_waitcnt vmcnt(0)" ::: "memory");
  __builtin_amdgcn_s_barrier();
  __builtin_amdgcn_sched_barrier(0);

  for (int kt = 0; kt < 32; ++kt) {
    const int cur = kt & 1;
    if (kt + 1 < 32) STAGE(kt + 1, cur ^ 1);       // DMA overlaps compute below
    __builtin_amdgcn_sched_barrier(0);

    #pragma unroll
    for (int ks = 0; ks < 2; ++ks) {
      f16x8 af[4], bf[4];
      #pragma unroll
      for (int f = 0; f < 4; ++f) {
        int ar = wr + f * 16 + lr;
        af[f] = *reinterpret_cast<const f16x8*>((const char*)As[cur] + ar * 128 +
                                                ((ks * 64 + lg * 16) ^ swzx(ar)));
        int br = wc + f * 16 + lr;
        bf[f] = *reinterpret_cast<const f16x8*>((const char*)Bs[cur] + br * 128 +
                                                ((ks * 64 + lg * 16) ^ swzx(br)));
      }
      __builtin_amdgcn_s_setprio(1);
      #pragma unroll
      for (int i = 0; i < 4; ++i)
        #pragma unroll
        for (int j = 0; j < 4; ++j)
          acc[i][j] = __builtin_amdgcn_mfma_f32_16x16x32_f16(af[i], bf[j], acc[i][j], 0, 0, 0);
      __builtin_amdgcn_s_setprio(0);
    }

    // next tile's DMA landed (hidden under the 32 MFMAs above); rotate
    asm volatile("s_waitcnt vmcnt(0)" ::: "memory");
    __builtin_amdgcn_s_barrier();
    __builtin_amdgcn_sched_barrier(0);
  }

  #pragma unroll
  for (int fm = 0; fm < 4; ++fm)
    #pragma unroll
    for (int fn = 0; fn < 4; ++fn)
      #pragma unroll
      for (int r = 0; r < 4; ++r) {
        int grow = bm * 128 + wr + fm * 16 + lg * 4 + r;   // D row = (lane>>4)*4+r
        int gcol = bn * 128 + wc + fn * 16 + lr;           // D col = lane&15
        float v = acc[fm][fn][r];
        size_t o = (size_t)grow * ldc + gcol;
        if (OUTF32) ((float*)C)[o] = v;
        else        ((_Float16*)C)[o] = (_Float16)v;
      }
}

// ---------------- fused masked attention + RMSNorm, fp16 1-pass ----------
// 4 waves (256 thr), QBLK=64, KVBLK=64. grid (32, 16): block j does q-tiles
// {j, 31-j} -> uniform 33 KV-tile-units; 512 blocks = 2/CU co-resident.
__global__ __launch_bounds__(256) void k_attn1(const _Float16* __restrict__ qkv,
                                               const _Float16* __restrict__ vt,
                                               const float* __restrict__ nm,
                                               const float* __restrict__ rms_scale,
                                               _Float16* __restrict__ y) {
  __shared__ __align__(16) _Float16 Ks[2][64 * 128];   // [m][k] 16KB x2
  __shared__ __align__(16) _Float16 Vs[2][128 * 64];   // [v][m] 16KB x2
  __shared__ __align__(16) _Float16 Ps[64 * 64];       // [n][m] 8KB
  const int tid = threadIdx.x;
  const int lane = tid & 63, w = tid >> 6;             // w in 0..3
  const int lr = lane & 15, lg = lane >> 4;
  const int bh = blockIdx.x, b = bh >> 4, h = bh & 15;
  const _Float16* qb = qkv + (size_t)b * 2048 * 6144 + h * 128;          // q cols
  const _Float16* kb = qkv + (size_t)b * 2048 * 6144 + 2048 + h * 128;   // k cols
  const size_t vbase = (size_t)bh * 128 * 2048;                          // (bh,v,n)

  const int krow = tid >> 4, kc = tid & 15;    // K stage: 16 rows/it, 16 chunks
  const int vrow = tid >> 3, vc = tid & 7;     // V stage: 32 rows/it, 8 chunks

  auto STAGE = [&](int t, int bufi) {
    #pragma unroll
    for (int it = 0; it < 4; ++it) {
      int kr = it * 16 + krow;
      int gk = ((kc * 16) ^ swzx(kr)) >> 1;
      gld16(kb + (size_t)(t * 64 + kr) * 6144 + gk,
            (char*)Ks[bufi] + it * 4096 + tid * 16);   // 16 rows x 256 B per it
      int vr = it * 32 + vrow;
      int gv = ((vc * 16) ^ swzx(vr)) >> 1;
      gld16(vt + vbase + (size_t)vr * 2048 + t * 64 + gv,
            (char*)Vs[bufi] + it * 4096 + tid * 16);   // 32 rows x 128 B per it
    }
  };

  #pragma unroll
  for (int pi = 0; pi < 2; ++pi) {
    const int qt = pi ? (31 - (int)blockIdx.y) : (int)blockIdx.y;  // 64-row q-tile
    const int nT = qt + 1;

    f16x8 aq[4];
    {
      const _Float16* qrow = qb + (size_t)(qt * 64 + w * 16 + lr) * 6144;
      #pragma unroll
      for (int ks = 0; ks < 4; ++ks)
        aq[ks] = *reinterpret_cast<const f16x8*>(qrow + ks * 32 + lg * 8);
    }

    f32x4 accY[8];
    #pragma unroll
    for (int i = 0; i < 8; ++i) { f32x4 z = {0.f, 0.f, 0.f, 0.f}; accY[i] = z; }

    STAGE(0, 0);
    asm volatile("s_waitcnt vmcnt(0)" ::: "memory");
    __builtin_amdgcn_s_barrier();
    __builtin_amdgcn_sched_barrier(0);

    for (int t = 0; t < nT; ++t) {
      const int cur = t & 1;

      float nmv[4][4];                            // mask for tile t -- FIRST
      #pragma unroll
      for (int fm = 0; fm < 4; ++fm)
        #pragma unroll
        for (int r = 0; r < 4; ++r)
          nmv[fm][r] = nm[(size_t)(qt * 64 + w * 16 + lg * 4 + r) * 2048 +
                          t * 64 + fm * 16 + lr];
      __builtin_amdgcn_sched_barrier(0);          // pin: nm loads before DMA

      if (t + 1 < nT) STAGE(t + 1, cur ^ 1);      // DMA overlaps compute below

      f32x4 accS[4];
      #pragma unroll
      for (int i = 0; i < 4; ++i) { f32x4 z = {0.f, 0.f, 0.f, 0.f}; accS[i] = z; }
      __builtin_amdgcn_s_setprio(1);
      #pragma unroll
      for (int ks = 0; ks < 4; ++ks) {
        #pragma unroll
        for (int fm = 0; fm < 4; ++fm) {
          int br = fm * 16 + lr;
          f16x8 bk = *reinterpret_cast<const f16x8*>(
              (const char*)Ks[cur] + br * 256 + ((ks * 64 + lg * 16) ^ swzx(br)));
          accS[fm] = __builtin_amdgcn_mfma_f32_16x16x32_f16(aq[ks], bk, accS[fm], 0, 0, 0);
        }
      }
      __builtin_amdgcn_s_setprio(0);

      #pragma unroll
      for (int fm = 0; fm < 4; ++fm)
        #pragma unroll
        for (int r = 0; r < 4; ++r) {
          float pv = accS[fm][r] * nmv[fm][r];
          int pr = w * 16 + lg * 4 + r, pc = fm * 16 + lr;
          *reinterpret_cast<_Float16*>((char*)Ps + pr * 128 + ((pc * 2) ^ swzx(pr))) =
              (_Float16)pv;
        }

      __builtin_amdgcn_s_setprio(1);
      #pragma unroll
      for (int ks = 0; ks < 2; ++ks) {
        int ar = w * 16 + lr;
        f16x8 ap = *reinterpret_cast<const f16x8*>(
            (const char*)Ps + ar * 128 + ((ks * 64 + lg * 16) ^ swzx(ar)));
        #pragma unroll
        for (int fv = 0; fv < 8; ++fv) {
          int br = fv * 16 + lr;
          f16x8 bv = *reinterpret_cast<const f16x8*>(
              (const char*)Vs[cur] + br * 128 + ((ks * 64 + lg * 16) ^ swzx(br)));
          accY[fv] = __builtin_amdgcn_mfma_f32_16x16x32_f16(ap, bv, accY[fv], 0, 0, 0);
        }
      }
      __builtin_amdgcn_s_setprio(0);

      asm volatile("s_waitcnt vmcnt(0)" ::: "memory");
      __builtin_amdgcn_s_barrier();
      __builtin_amdgcn_sched_barrier(0);
    }

    // epilogue: RMSNorm over V=128 per row, write y fp16 (b,n,h,v)
    #pragma unroll
    for (int r = 0; r < 4; ++r) {
      float sq = 0.f;
      #pragma unroll
      for (int fv = 0; fv < 8; ++fv) { float yy = accY[fv][r]; sq += yy * yy; }
      sq += __shfl_xor(sq, 1); sq += __shfl_xor(sq, 2);
      sq += __shfl_xor(sq, 4); sq += __shfl_xor(sq, 8);
      float scale = rsqrtf(sq * (1.0f / 128.0f) + 1e-6f);
      int nrow = qt * 64 + w * 16 + lg * 4 + r;
      size_t orow = ((size_t)b * 2048 + nrow) * 2048 + (size_t)h * 128;
      #pragma unroll
      for (int fv = 0; fv < 8; ++fv) {
        int col = fv * 16 + lr;
        y[orow + col] = (_Float16)(accY[fv][r] * scale * rms_scale[col]);
      }
    }
  }
}

extern "C" void kernel_launch(void* const* d_in, const int* in_sizes, int n_in,
                              void* d_out, int out_size, void* d_ws, size_t ws_size,
                              hipStream_t stream) {
  (void)in_sizes; (void)n_in; (void)out_size; (void)ws_size;
  const float* x  = (const float*)d_in[0];
  const float* nm = (const float*)d_in[1];
  const float* wq = (const float*)d_in[2];
  const float* wk = (const float*)d_in[3];
  const float* wv = (const float*)d_in[4];
  const float* rs = (const float*)d_in[5];
  const float* wo = (const float*)d_in[6];

  _Float16* p = (_Float16*)d_ws;                 // ~118 MB of fp16 planes
  _Float16* xf  = p; p += 8388608;               // x fp16; reused as y after attn
  _Float16* wt3 = p; p += 12582912;              // [wqT; wkT; wvT] (6144 x 2048)
  _Float16* wto = p; p += 4194304;               // woT
  _Float16* qkv = p; p += 25165824;              // (b,n) x (q|k|v) (4096 x 6144)
  _Float16* vtf = p; p += 8388608;               // v^T (b*h, v, n)

  k_cast_h<<<dim3(2048), dim3(256), 0, stream>>>(x, xf, 8388608);

  k_transpose_h4<<<dim3(64, 64, 4), dim3(32, 8), 0, stream>>>(
      wq, wk, wv, wo, wt3, wt3 + 4194304, wt3 + 8388608, wto);

  // merged q|k|v projection: C (4096 x 6144), BK=64 dbuf, 2 blocks/CU
  k_gemm_db<0><<<dim3(48, 32), dim3(256), 0, stream>>>(xf, wt3, qkv, 6144);
  k_transpose_v<<<dim3(4, 64, 32), dim3(32, 8), 0, stream>>>(qkv, vtf);

  // y written into the (now dead) x plane
  k_attn1<<<dim3(32, 16), dim3(256), 0, stream>>>(qkv, vtf, nm, rs, xf);

  k_gemm_db<1><<<dim3(16, 32), dim3(256), 0, stream>>>(xf, wto, d_out, 2048);
}